// Round 3
// baseline (151.243 us; speedup 1.0000x reference)
//
#include <hip/hip_runtime.h>

#define NCH 30
#define CELLS 128                  // cells per block (256 threads)
#define NF4   (CELLS * NCH / 4)   // 960 float4 per array per block

__global__ void __launch_bounds__(256) yolo_loss_main(
    const float* __restrict__ pred,
    const float* __restrict__ targ,
    float* __restrict__ partial,   // [gridDim.x][4]
    int ncells)
{
    __shared__ float lp[CELLS * NCH];   // 15360 B
    __shared__ float lt[CELLS * NCH];   // 15360 B

    const int tid = threadIdx.x;
    const size_t baseF4 = (size_t)blockIdx.x * NF4;

    const float4* p4 = (const float4*)pred;
    const float4* t4 = (const float4*)targ;
    float4* lp4 = (float4*)lp;
    float4* lt4 = (float4*)lt;

    // issue ALL global loads first (max MLP), then LDS writes
    float4 rp_[4], rt_[4];
    #pragma unroll
    for (int i = 0; i < 4; ++i) {
        int li = tid + i * 256;            // guard is wave-uniform (960 = 15 waves' worth)
        if (li < NF4) { rp_[i] = p4[baseF4 + li]; rt_[i] = t4[baseF4 + li]; }
    }
    #pragma unroll
    for (int i = 0; i < 4; ++i) {
        int li = tid + i * 256;
        if (li < NF4) { lp4[li] = rp_[i]; lt4[li] = rt_[i]; }
    }
    __syncthreads();

    float s_xywh = 0.f, s_obj = 0.f, s_noobj = 0.f, s_cls = 0.f;
    int cell = blockIdx.x * CELLS + tid;
    if (tid < CELLS && cell < ncells) {
        const float2* cp2 = (const float2*)(lp + tid * NCH);
        const float2* ct2 = (const float2*)(lt + tid * NCH);
        float pv[NCH], tv[NCH];
        #pragma unroll
        for (int i = 0; i < 15; ++i) {
            float2 a = cp2[i]; pv[2*i] = a.x; pv[2*i+1] = a.y;
            float2 b = ct2[i]; tv[2*i] = b.x; tv[2*i+1] = b.y;
        }
        float conf_t = tv[4];
        float coord = (conf_t > 0.f)  ? 1.f : 0.f;
        float noobj = (conf_t == 0.f) ? 1.f : 0.f;

        float tcx = tv[0] / 7.0f, tcy = tv[1] / 7.0f;
        float tx0 = tcx - 0.5f * tv[2], ty0 = tcy - 0.5f * tv[3];
        float tx1 = tcx + 0.5f * tv[2], ty1 = tcy + 0.5f * tv[3];
        float area_t = (tx1 - tx0) * (ty1 - ty0);

        float iou[2];
        #pragma unroll
        for (int b = 0; b < 2; ++b) {
            const float* pb = pv + 5 * b;
            float cx = pb[0] / 7.0f, cy = pb[1] / 7.0f;
            float x0 = cx - 0.5f * pb[2], y0 = cy - 0.5f * pb[3];
            float x1 = cx + 0.5f * pb[2], y1 = cy + 0.5f * pb[3];
            float lx = fmaxf(x0, tx0), ly = fmaxf(y0, ty0);
            float rx = fminf(x1, tx1), ry = fminf(y1, ty1);
            float w = fmaxf(rx - lx, 0.f), h = fmaxf(ry - ly, 0.f);
            float inter = w * h;
            float area_p = (x1 - x0) * (y1 - y0);
            iou[b] = inter / (area_p + area_t - inter);
        }
        int best = (iou[1] > iou[0]) ? 1 : 0;   // argmax ties -> box 0
        float max_iou = fmaxf(iou[0], iou[1]);
        const float* rp = pv + 5 * best;

        float dx = rp[0] - tv[0], dy = rp[1] - tv[1];
        float dw = sqrtf(rp[2]) - sqrtf(tv[2]);
        float dh = sqrtf(rp[3]) - sqrtf(tv[3]);
        s_xywh = coord * (dx*dx + dy*dy + dw*dw + dh*dh);

        float dobj = rp[4] - max_iou;
        s_obj = coord * dobj * dobj;

        float cls = 0.f;
        #pragma unroll
        for (int c = 10; c < 30; ++c) { float d = pv[c] - tv[c]; cls += d * d; }
        s_cls = coord * cls;

        float d4 = pv[4] - tv[4], d9 = pv[9] - tv[9];
        s_noobj = noobj * (d4*d4 + d9*d9);
    }

    #pragma unroll
    for (int off = 32; off > 0; off >>= 1) {
        s_xywh  += __shfl_down(s_xywh, off);
        s_obj   += __shfl_down(s_obj, off);
        s_noobj += __shfl_down(s_noobj, off);
        s_cls   += __shfl_down(s_cls, off);
    }
    __shared__ float red[4][4];
    int wid = tid >> 6, lane = tid & 63;
    if (lane == 0) {
        red[wid][0] = s_xywh; red[wid][1] = s_obj;
        red[wid][2] = s_noobj; red[wid][3] = s_cls;
    }
    __syncthreads();
    if (tid == 0) {
        float a = 0.f, b = 0.f, c = 0.f, d = 0.f;
        #pragma unroll
        for (int w = 0; w < 4; ++w) {
            a += red[w][0]; b += red[w][1]; c += red[w][2]; d += red[w][3];
        }
        float4* out4 = (float4*)(partial + (size_t)blockIdx.x * 4);
        *out4 = make_float4(a, b, c, d);
    }
}

__global__ void __launch_bounds__(256) yolo_finalize(
    const float* __restrict__ partial, int nblocks,
    float* __restrict__ out, float inv_bs)
{
    int tid = threadIdx.x;
    float a = 0.f, b = 0.f, c = 0.f, d = 0.f;
    for (int r = tid; r < nblocks; r += 256) {
        const float4 v = *(const float4*)(partial + (size_t)r * 4);
        a += v.x; b += v.y; c += v.z; d += v.w;
    }
    #pragma unroll
    for (int off = 32; off > 0; off >>= 1) {
        a += __shfl_down(a, off);
        b += __shfl_down(b, off);
        c += __shfl_down(c, off);
        d += __shfl_down(d, off);
    }
    __shared__ float red[4][4];
    int wid = tid >> 6, lane = tid & 63;
    if (lane == 0) { red[wid][0]=a; red[wid][1]=b; red[wid][2]=c; red[wid][3]=d; }
    __syncthreads();
    if (tid == 0) {
        float xywh=0.f, obj=0.f, noobj=0.f, cls=0.f;
        #pragma unroll
        for (int w = 0; w < 4; ++w) {
            xywh += red[w][0]; obj += red[w][1];
            noobj += red[w][2]; cls += red[w][3];
        }
        out[0] = (5.0f * xywh + obj + 0.5f * noobj + cls) * inv_bs;
        out[1] = xywh;
        out[2] = obj;
        out[3] = noobj;
        out[4] = cls;
    }
}

extern "C" void kernel_launch(void* const* d_in, const int* in_sizes, int n_in,
                              void* d_out, int out_size, void* d_ws, size_t ws_size,
                              hipStream_t stream)
{
    const float* pred = (const float*)d_in[0];
    const float* targ = (const float*)d_in[1];
    float* out = (float*)d_out;
    float* partial = (float*)d_ws;

    int ncells = in_sizes[0] / NCH;          // 401408
    float inv_bs = 1.0f / (float)(ncells / 49);

    int grid = (ncells + CELLS - 1) / CELLS; // 3136
    yolo_loss_main<<<grid, 256, 0, stream>>>(pred, targ, partial, ncells);
    yolo_finalize<<<1, 256, 0, stream>>>(partial, grid, out, inv_bs);
}

// Round 4
// 116.208 us; speedup vs baseline: 1.3015x; 1.3015x over previous
//
#include <hip/hip_runtime.h>

#define NCH 30
#define CELLS 128                  // cells per block (256 threads)
#define NF4   (CELLS * NCH / 4)    // 960 float4 per array per block
#define NCHUNK 15                  // 960 float4 / 64 lanes = 15 wave-chunks of 1 KB

typedef __attribute__((address_space(3))) unsigned int lds_u32_t;
typedef __attribute__((address_space(1))) unsigned int glb_u32_t;

__global__ void __launch_bounds__(256) yolo_loss_main(
    const float* __restrict__ pred,
    const float* __restrict__ targ,
    float* __restrict__ partial,   // [gridDim.x][4]
    int ncells)
{
    __shared__ float lp[CELLS * NCH];   // 15360 B
    __shared__ float lt[CELLS * NCH];   // 15360 B

    const int tid  = threadIdx.x;
    const int lane = tid & 63;
    const int wv   = tid >> 6;

    const size_t baseFloat = (size_t)blockIdx.x * (CELLS * NCH);

    // global -> LDS direct DMA, 16 B/lane, wave-uniform LDS base per chunk.
    // chunk c covers floats [c*256, c*256+256) of this block's tile.
    #pragma unroll
    for (int i = 0; i < 4; ++i) {
        int chunk = wv + i * 4;              // wave-uniform, 0..15
        if (chunk < NCHUNK) {
            const float* gp = pred + baseFloat + chunk * 256 + lane * 4;
            const float* gt = targ + baseFloat + chunk * 256 + lane * 4;
            __builtin_amdgcn_global_load_lds((const glb_u32_t*)gp,
                                             (lds_u32_t*)(lp + chunk * 256), 16, 0, 0);
            __builtin_amdgcn_global_load_lds((const glb_u32_t*)gt,
                                             (lds_u32_t*)(lt + chunk * 256), 16, 0, 0);
        }
    }
    asm volatile("s_waitcnt vmcnt(0)" ::: "memory");
    __syncthreads();

    float s_xywh = 0.f, s_obj = 0.f, s_noobj = 0.f, s_cls = 0.f;
    int cell = blockIdx.x * CELLS + tid;
    if (tid < CELLS && cell < ncells) {
        const float2* cp2 = (const float2*)(lp + tid * NCH);
        const float2* ct2 = (const float2*)(lt + tid * NCH);
        float pv[NCH], tv[NCH];
        #pragma unroll
        for (int i = 0; i < 15; ++i) {
            float2 a = cp2[i]; pv[2*i] = a.x; pv[2*i+1] = a.y;
            float2 b = ct2[i]; tv[2*i] = b.x; tv[2*i+1] = b.y;
        }
        float conf_t = tv[4];
        float coord = (conf_t > 0.f)  ? 1.f : 0.f;
        float noobj = (conf_t == 0.f) ? 1.f : 0.f;

        float tcx = tv[0] / 7.0f, tcy = tv[1] / 7.0f;
        float tx0 = tcx - 0.5f * tv[2], ty0 = tcy - 0.5f * tv[3];
        float tx1 = tcx + 0.5f * tv[2], ty1 = tcy + 0.5f * tv[3];
        float area_t = (tx1 - tx0) * (ty1 - ty0);

        float iou[2];
        #pragma unroll
        for (int b = 0; b < 2; ++b) {
            const float* pb = pv + 5 * b;
            float cx = pb[0] / 7.0f, cy = pb[1] / 7.0f;
            float x0 = cx - 0.5f * pb[2], y0 = cy - 0.5f * pb[3];
            float x1 = cx + 0.5f * pb[2], y1 = cy + 0.5f * pb[3];
            float lx = fmaxf(x0, tx0), ly = fmaxf(y0, ty0);
            float rx = fminf(x1, tx1), ry = fminf(y1, ty1);
            float w = fmaxf(rx - lx, 0.f), h = fmaxf(ry - ly, 0.f);
            float inter = w * h;
            float area_p = (x1 - x0) * (y1 - y0);
            iou[b] = inter / (area_p + area_t - inter);
        }
        int best = (iou[1] > iou[0]) ? 1 : 0;   // argmax ties -> box 0
        float max_iou = fmaxf(iou[0], iou[1]);
        const float* rp = pv + 5 * best;

        float dx = rp[0] - tv[0], dy = rp[1] - tv[1];
        float dw = sqrtf(rp[2]) - sqrtf(tv[2]);
        float dh = sqrtf(rp[3]) - sqrtf(tv[3]);
        s_xywh = coord * (dx*dx + dy*dy + dw*dw + dh*dh);

        float dobj = rp[4] - max_iou;
        s_obj = coord * dobj * dobj;

        float cls = 0.f;
        #pragma unroll
        for (int c = 10; c < 30; ++c) { float d = pv[c] - tv[c]; cls += d * d; }
        s_cls = coord * cls;

        float d4 = pv[4] - tv[4], d9 = pv[9] - tv[9];
        s_noobj = noobj * (d4*d4 + d9*d9);
    }

    #pragma unroll
    for (int off = 32; off > 0; off >>= 1) {
        s_xywh  += __shfl_down(s_xywh, off);
        s_obj   += __shfl_down(s_obj, off);
        s_noobj += __shfl_down(s_noobj, off);
        s_cls   += __shfl_down(s_cls, off);
    }
    __shared__ float red[4][4];
    int wid = tid >> 6, lane2 = tid & 63;
    if (lane2 == 0) {
        red[wid][0] = s_xywh; red[wid][1] = s_obj;
        red[wid][2] = s_noobj; red[wid][3] = s_cls;
    }
    __syncthreads();
    if (tid == 0) {
        float a = 0.f, b = 0.f, c = 0.f, d = 0.f;
        #pragma unroll
        for (int w = 0; w < 4; ++w) {
            a += red[w][0]; b += red[w][1]; c += red[w][2]; d += red[w][3];
        }
        float4* out4 = (float4*)(partial + (size_t)blockIdx.x * 4);
        *out4 = make_float4(a, b, c, d);
    }
}

__global__ void __launch_bounds__(256) yolo_finalize(
    const float* __restrict__ partial, int nblocks,
    float* __restrict__ out, float inv_bs)
{
    int tid = threadIdx.x;
    float a = 0.f, b = 0.f, c = 0.f, d = 0.f;
    for (int r = tid; r < nblocks; r += 256) {
        const float4 v = *(const float4*)(partial + (size_t)r * 4);
        a += v.x; b += v.y; c += v.z; d += v.w;
    }
    #pragma unroll
    for (int off = 32; off > 0; off >>= 1) {
        a += __shfl_down(a, off);
        b += __shfl_down(b, off);
        c += __shfl_down(c, off);
        d += __shfl_down(d, off);
    }
    __shared__ float red[4][4];
    int wid = tid >> 6, lane = tid & 63;
    if (lane == 0) { red[wid][0]=a; red[wid][1]=b; red[wid][2]=c; red[wid][3]=d; }
    __syncthreads();
    if (tid == 0) {
        float xywh=0.f, obj=0.f, noobj=0.f, cls=0.f;
        #pragma unroll
        for (int w = 0; w < 4; ++w) {
            xywh += red[w][0]; obj += red[w][1];
            noobj += red[w][2]; cls += red[w][3];
        }
        out[0] = (5.0f * xywh + obj + 0.5f * noobj + cls) * inv_bs;
        out[1] = xywh;
        out[2] = obj;
        out[3] = noobj;
        out[4] = cls;
    }
}

extern "C" void kernel_launch(void* const* d_in, const int* in_sizes, int n_in,
                              void* d_out, int out_size, void* d_ws, size_t ws_size,
                              hipStream_t stream)
{
    const float* pred = (const float*)d_in[0];
    const float* targ = (const float*)d_in[1];
    float* out = (float*)d_out;
    float* partial = (float*)d_ws;

    int ncells = in_sizes[0] / NCH;          // 401408
    float inv_bs = 1.0f / (float)(ncells / 49);

    int grid = (ncells + CELLS - 1) / CELLS; // 3136
    yolo_loss_main<<<grid, 256, 0, stream>>>(pred, targ, partial, ncells);
    yolo_finalize<<<1, 256, 0, stream>>>(partial, grid, out, inv_bs);
}

// Round 5
// 114.764 us; speedup vs baseline: 1.3179x; 1.0126x over previous
//
#include <hip/hip_runtime.h>

#define NCH 30
#define TILE_CELLS 128
#define TILE_FLOATS (TILE_CELLS * NCH)   // 3840 floats = 15 chunks of 256
#define GRID_MAIN 512                    // 2 blocks/CU

typedef __attribute__((address_space(3))) unsigned int lds_u32_t;
typedef __attribute__((address_space(1))) unsigned int glb_u32_t;

// Issue one tile's global->LDS DMA. 30 combined chunks (15 pred + 15 targ),
// chunk c: array = c&1, chunk index = c>>1. Wave w takes c = w, w+4, ...
// -> waves 0,1 issue 8 loads; waves 2,3 issue 7.
__device__ __forceinline__ void issue_tile(
    const float* __restrict__ pred, const float* __restrict__ targ,
    float* ldsP, float* ldsT, size_t tileBase, int wv, int lane)
{
    #pragma unroll
    for (int c = 0; c < 30; ++c) {
        if ((c & 3) == wv) {
            const int ci = c >> 1;
            const float* g = ((c & 1) ? targ : pred) + tileBase + ci * 256 + lane * 4;
            float* l = ((c & 1) ? ldsT : ldsP) + ci * 256;
            __builtin_amdgcn_global_load_lds((const glb_u32_t*)g, (lds_u32_t*)l, 16, 0, 0);
        }
    }
}

__global__ void __launch_bounds__(256) yolo_loss_main(
    const float* __restrict__ pred,
    const float* __restrict__ targ,
    float* __restrict__ partial,   // [GRID_MAIN][4]
    int ncells)
{
    __shared__ float bufP[2][TILE_FLOATS];   // 2 x 15360 B
    __shared__ float bufT[2][TILE_FLOATS];   // 2 x 15360 B
    __shared__ float red[4][4];

    const int tid  = threadIdx.x;
    const int lane = tid & 63;
    const int wv   = tid >> 6;
    const int ntiles = ncells / TILE_CELLS;  // 3136
    const int stride = gridDim.x;            // 512

    float s_xywh = 0.f, s_obj = 0.f, s_noobj = 0.f, s_cls = 0.f;

    int t = blockIdx.x;
    // prologue: prefetch first tile into buf 0
    issue_tile(pred, targ, bufP[0], bufT[0], (size_t)t * TILE_FLOATS, wv, lane);

    int cur = 0;
    for (; t < ntiles; t += stride) {
        int nt = t + stride;
        if (nt < ntiles) {
            issue_tile(pred, targ, bufP[cur ^ 1], bufT[cur ^ 1],
                       (size_t)nt * TILE_FLOATS, wv, lane);
            // own outstanding = next tile's loads -> current tile complete
            if (wv < 2) asm volatile("s_waitcnt vmcnt(8)" ::: "memory");
            else        asm volatile("s_waitcnt vmcnt(7)" ::: "memory");
        } else {
            asm volatile("s_waitcnt vmcnt(0)" ::: "memory");
        }
        __builtin_amdgcn_s_barrier();   // raw barrier: do NOT drain vmcnt

        if (tid < TILE_CELLS) {
            const float2* cp2 = (const float2*)(bufP[cur] + tid * NCH);
            const float2* ct2 = (const float2*)(bufT[cur] + tid * NCH);
            float pv[NCH], tv[NCH];
            #pragma unroll
            for (int i = 0; i < 15; ++i) {
                float2 a = cp2[i]; pv[2*i] = a.x; pv[2*i+1] = a.y;
                float2 b = ct2[i]; tv[2*i] = b.x; tv[2*i+1] = b.y;
            }
            float conf_t = tv[4];
            float coord = (conf_t > 0.f)  ? 1.f : 0.f;
            float noobj = (conf_t == 0.f) ? 1.f : 0.f;

            float tcx = tv[0] / 7.0f, tcy = tv[1] / 7.0f;
            float tx0 = tcx - 0.5f * tv[2], ty0 = tcy - 0.5f * tv[3];
            float tx1 = tcx + 0.5f * tv[2], ty1 = tcy + 0.5f * tv[3];
            float area_t = (tx1 - tx0) * (ty1 - ty0);

            float iou[2];
            #pragma unroll
            for (int b = 0; b < 2; ++b) {
                const float* pb = pv + 5 * b;
                float cx = pb[0] / 7.0f, cy = pb[1] / 7.0f;
                float x0 = cx - 0.5f * pb[2], y0 = cy - 0.5f * pb[3];
                float x1 = cx + 0.5f * pb[2], y1 = cy + 0.5f * pb[3];
                float lx = fmaxf(x0, tx0), ly = fmaxf(y0, ty0);
                float rx = fminf(x1, tx1), ry = fminf(y1, ty1);
                float w = fmaxf(rx - lx, 0.f), h = fmaxf(ry - ly, 0.f);
                float inter = w * h;
                float area_p = (x1 - x0) * (y1 - y0);
                iou[b] = inter / (area_p + area_t - inter);
            }
            int best = (iou[1] > iou[0]) ? 1 : 0;   // argmax ties -> box 0
            float max_iou = fmaxf(iou[0], iou[1]);
            const float* rp = pv + 5 * best;

            float dx = rp[0] - tv[0], dy = rp[1] - tv[1];
            float dw = sqrtf(rp[2]) - sqrtf(tv[2]);
            float dh = sqrtf(rp[3]) - sqrtf(tv[3]);
            s_xywh += coord * (dx*dx + dy*dy + dw*dw + dh*dh);

            float dobj = rp[4] - max_iou;
            s_obj += coord * dobj * dobj;

            float cls = 0.f;
            #pragma unroll
            for (int c = 10; c < 30; ++c) { float d = pv[c] - tv[c]; cls += d * d; }
            s_cls += coord * cls;

            float d4 = pv[4] - tv[4], d9 = pv[9] - tv[9];
            s_noobj += noobj * (d4*d4 + d9*d9);
        }
        __builtin_amdgcn_s_barrier();   // buffer free before next overwrite
        cur ^= 1;
    }

    // final block reduction (loads all drained: last iter waited vmcnt(0))
    #pragma unroll
    for (int off = 32; off > 0; off >>= 1) {
        s_xywh  += __shfl_down(s_xywh, off);
        s_obj   += __shfl_down(s_obj, off);
        s_noobj += __shfl_down(s_noobj, off);
        s_cls   += __shfl_down(s_cls, off);
    }
    if (lane == 0) {
        red[wv][0] = s_xywh; red[wv][1] = s_obj;
        red[wv][2] = s_noobj; red[wv][3] = s_cls;
    }
    __syncthreads();
    if (tid == 0) {
        float a = 0.f, b = 0.f, c = 0.f, d = 0.f;
        #pragma unroll
        for (int w = 0; w < 4; ++w) {
            a += red[w][0]; b += red[w][1]; c += red[w][2]; d += red[w][3];
        }
        float4* out4 = (float4*)(partial + (size_t)blockIdx.x * 4);
        *out4 = make_float4(a, b, c, d);
    }
}

__global__ void __launch_bounds__(256) yolo_finalize(
    const float* __restrict__ partial, int nblocks,
    float* __restrict__ out, float inv_bs)
{
    int tid = threadIdx.x;
    float a = 0.f, b = 0.f, c = 0.f, d = 0.f;
    for (int r = tid; r < nblocks; r += 256) {
        const float4 v = *(const float4*)(partial + (size_t)r * 4);
        a += v.x; b += v.y; c += v.z; d += v.w;
    }
    #pragma unroll
    for (int off = 32; off > 0; off >>= 1) {
        a += __shfl_down(a, off);
        b += __shfl_down(b, off);
        c += __shfl_down(c, off);
        d += __shfl_down(d, off);
    }
    __shared__ float red[4][4];
    int wid = tid >> 6, lane = tid & 63;
    if (lane == 0) { red[wid][0]=a; red[wid][1]=b; red[wid][2]=c; red[wid][3]=d; }
    __syncthreads();
    if (tid == 0) {
        float xywh=0.f, obj=0.f, noobj=0.f, cls=0.f;
        #pragma unroll
        for (int w = 0; w < 4; ++w) {
            xywh += red[w][0]; obj += red[w][1];
            noobj += red[w][2]; cls += red[w][3];
        }
        out[0] = (5.0f * xywh + obj + 0.5f * noobj + cls) * inv_bs;
        out[1] = xywh;
        out[2] = obj;
        out[3] = noobj;
        out[4] = cls;
    }
}

extern "C" void kernel_launch(void* const* d_in, const int* in_sizes, int n_in,
                              void* d_out, int out_size, void* d_ws, size_t ws_size,
                              hipStream_t stream)
{
    const float* pred = (const float*)d_in[0];
    const float* targ = (const float*)d_in[1];
    float* out = (float*)d_out;
    float* partial = (float*)d_ws;

    int ncells = in_sizes[0] / NCH;          // 401408 = 3136 tiles of 128
    float inv_bs = 1.0f / (float)(ncells / 49);

    yolo_loss_main<<<GRID_MAIN, 256, 0, stream>>>(pred, targ, partial, ncells);
    yolo_finalize<<<1, 256, 0, stream>>>(partial, GRID_MAIN, out, inv_bs);
}